// Round 3
// baseline (682.227 us; speedup 1.0000x reference)
//
#include <hip/hip_runtime.h>

// Problem constants (QuantLinear: x[M,K] fp32, qweight[K,N/8] i32, qzeros[G,N/8] i32,
// scales[G,N] fp32, bias[N] fp32, groupsize=128) -> out[M,N] fp32
#define M_DIM 4096
#define N_DIM 12288
#define K_DIM 4096
#define NP    1536        // N/8 packed words per row
#define GS    128

typedef unsigned short ushort_t;
typedef _Float16 half8 __attribute__((ext_vector_type(8)));
typedef unsigned short us8 __attribute__((ext_vector_type(8)));
typedef float f32x16 __attribute__((ext_vector_type(16)));
typedef float f32x4 __attribute__((ext_vector_type(4)));

__device__ __forceinline__ unsigned short f2h(float f) {
  _Float16 h = (_Float16)f;
  return __builtin_bit_cast(unsigned short, h);
}

// async global->LDS, 16B per lane; LDS dst is wave-uniform base + lane*16
#define GLDS16(G, L) __builtin_amdgcn_global_load_lds(                      \
    (const __attribute__((address_space(1))) void*)(G),                     \
    (__attribute__((address_space(3))) void*)(L), 16, 0, 0)

#define DQ_BLOCKS (96 * 64)                   // dequant: 96 n-tiles x 64 k-tiles
#define CVT_BLOCKS (M_DIM * K_DIM / 8 / 256)  // 8192 (8 f16 per thread, R1 form)

// ---------------------------------------------------------------------------
// Fused prep: blocks [0, DQ_BLOCKS) dequant qweight -> Wt[N,K] f16 (LDS tile
// transpose: coalesced reads, 64B-run writes). Blocks after that convert
// x fp32 -> f16 (8 elem/thread, 32B stride — R1 form; R2's 64B-stride 16-elem
// variant was the only suspect in a prep residual regression).
__global__ __launch_bounds__(256) void prep_kernel(
    const int* __restrict__ qw, const int* __restrict__ qz,
    const float* __restrict__ sc, ushort_t* __restrict__ wt,
    const float* __restrict__ x, ushort_t* __restrict__ xb) {
  __shared__ int ldsQ[64 * 16];
  __shared__ int ldsZ[16];
  const int tid = threadIdx.x;
  if (blockIdx.x >= DQ_BLOCKS) {
    // ---- x fp32 -> f16, 8 elements/thread
    size_t cid = (size_t)(blockIdx.x - DQ_BLOCKS) * 256 + tid;
    const float4* p = (const float4*)(x + cid * 8);
    float4 a = p[0], b = p[1];
    us8 o;
    o[0] = f2h(a.x); o[1] = f2h(a.y); o[2] = f2h(a.z); o[3] = f2h(a.w);
    o[4] = f2h(b.x); o[5] = f2h(b.y); o[6] = f2h(b.z); o[7] = f2h(b.w);
    *(us8*)(xb + cid * 8) = o;
    return;
  }
  const int bx = blockIdx.x % 96;     // n-tile
  const int by = blockIdx.x / 96;     // k-tile
  const int k0 = by * 64;
  const int n0 = bx * 128;
  const int w0 = n0 >> 3;       // first packed word column of tile
  const int g  = k0 >> 7;       // 64-k tile lies inside one group (GS=128)
  {
    // 64 rows x 16 words; thread = (row, 4-word chunk): one int4 load each
    int row = tid >> 2, qc = tid & 3;
    int4 v = *(const int4*)(qw + (size_t)(k0 + row) * NP + w0 + qc * 4);
    ldsQ[row * 16 + ((qc * 4 + 0) ^ (row & 15))] = v.x;
    ldsQ[row * 16 + ((qc * 4 + 1) ^ (row & 15))] = v.y;
    ldsQ[row * 16 + ((qc * 4 + 2) ^ (row & 15))] = v.z;
    ldsQ[row * 16 + ((qc * 4 + 3) ^ (row & 15))] = v.w;
  }
  if (tid < 16) ldsZ[tid] = qz[g * NP + w0 + tid];
  __syncthreads();
  const int nl  = tid >> 1;     // local n 0..127
  const int kh  = tid & 1;      // which 32-k half
  const int col = nl >> 3;
  const int j4  = (nl & 7) * 4;
  const int z   = (ldsZ[col] >> j4) & 0xF;
  const float s = sc[(size_t)g * N_DIM + n0 + nl];
  ushort_t* dst = wt + (size_t)(n0 + nl) * K_DIM + k0 + kh * 32;
#pragma unroll
  for (int c = 0; c < 4; ++c) {
    us8 o;
#pragma unroll
    for (int ii = 0; ii < 8; ++ii) {
      int row = kh * 32 + c * 8 + ii;
      int q = (ldsQ[row * 16 + (col ^ (row & 15))] >> j4) & 0xF;
      o[ii] = f2h((float)(q - z) * s);
    }
    *(us8*)(dst + c * 8) = o;
  }
}

// ---------------------------------------------------------------------------
// R6 GEMM: 256x256 tile, BK=64 (2 staging units of 32k), 512 threads = 8
// waves (2m x 4n), wave tile 128x64 of mfma_f32_32x32x16_f16 (4m x 2n frags).
//
// R6 change vs R5 (370us, MfmaUtil 53%): register double-buffer at 16-k-step
// granularity. Each step's 6 ds_read_b128 are issued one step EARLY, so
// every 8-MFMA cluster runs wait-free (its data was requested ~500+ cyc
// before). 32x32x16 frags make this fit the register budget: frag set =
// 6 b128 = 24 VGPR, two sets = 48 (same as R5's single 16x16 set); total
// ~240 < 256 so the 512-thread block still gets 2 waves/SIMD.
// MFMA pipe also drops: 128 mfma(32x32) x 8.07cy = 1033 cyc/CU/phase vs
// 1242 for 16x16. New phase floor ~= LDS pipe (96 b128 x 12 = 1152) + sync.
//
// Frag layouts (harness-verified by the R3 kernel, m74/m101):
//   A/B: row=lane&31, k=(lane>>5)*8+j.  C/D: col=lane&31,
//   row=(reg&3)+8*(reg>>2)+4*(lane>>5).
//
// LDS ring: 4 units x 32KiB (unit u = 32-k step: A[256x32]+B[256x32]).
// A base (halfwords) = ((u&2)<<14) + ((u&1)<<13); slices (16k) at +0/+4096;
// B = A + 16384. Slot swizzle (both-sides, verified 0 conflicts):
// slot = h ^ ((row>>2)&1) -> lane-pure on the read side:
// loff = (lane&31)*16 + ((lane>>5)^((lane>>2)&1))*8.
//
// Schedule per phase q (stage at phase START, after the previous end
// barrier => all waves' unit-(q-1) reads provably drained before any wave's
// stage(q+3) writes can land — same WAR argument as R5):
//   stage(q+3)
//   load set1 <- unit q slice1   ; lgkmcnt(6) drains set0 ; 8 MFMA(set0)
//   load set0 <- unit q+1 slice0 ; lgkmcnt(6) drains set1 ; 8 MFMA(set1)
//   vmcnt(4)  (leaves q+3 in flight; guarantees unit q+1 landed, which the
//              NEXT phase's mid-phase read of unit q+2... and this phase's
//              own mid-phase read relied on the PREVIOUS phase's vmcnt(4))
//   s_barrier
// Prologue vmcnt(4) guarantees units 0 AND 1 landed before phase 0.

__device__ __forceinline__ void stage_unit(
    int u, const ushort_t* __restrict__ Ag, const ushort_t* __restrict__ Bg,
    int m0, int n0, int tid, ushort_t* lds) {
  const int b   = (u >> 1) & 1;
  const int ks  = u & 1;
  const int kbu = (u >> 1) * 64 + ks * 32;     // k base of this unit
  const int r   = tid >> 1;                    // row 0..255 (2 threads/row)
  // dest is LINEAR (tid*16B); source k-half inverse-swizzled: the data in
  // slot (tid&1) is global 8-k half (tid&1)^((row>>2)&1).
  const int hp  = (tid & 1) ^ ((tid >> 3) & 1);
  const size_t ka = (size_t)kbu + hp * 8;
  ushort_t* dA = lds + b * 32768 + (2 * ks) * 4096 + tid * 8;
  ushort_t* dB = dA + 16384;
  const ushort_t* sA = Ag + (size_t)(m0 + r) * K_DIM + ka;
  const ushort_t* sB = Bg + (size_t)(n0 + r) * K_DIM + ka;
  GLDS16(sA,      dA);          // A slice 2ks
  GLDS16(sA + 16, dA + 4096);   // A slice 2ks+1
  GLDS16(sB,      dB);          // B slice 2ks
  GLDS16(sB + 16, dB + 4096);   // B slice 2ks+1
}

#define SB() __builtin_amdgcn_sched_barrier(0)

#define MFMA8(A, B)                                                           \
  do {                                                                        \
    acc[0][0] = __builtin_amdgcn_mfma_f32_32x32x16_f16(A[0], B[0], acc[0][0], 0, 0, 0); \
    acc[0][1] = __builtin_amdgcn_mfma_f32_32x32x16_f16(A[0], B[1], acc[0][1], 0, 0, 0); \
    acc[1][0] = __builtin_amdgcn_mfma_f32_32x32x16_f16(A[1], B[0], acc[1][0], 0, 0, 0); \
    acc[1][1] = __builtin_amdgcn_mfma_f32_32x32x16_f16(A[1], B[1], acc[1][1], 0, 0, 0); \
    acc[2][0] = __builtin_amdgcn_mfma_f32_32x32x16_f16(A[2], B[0], acc[2][0], 0, 0, 0); \
    acc[2][1] = __builtin_amdgcn_mfma_f32_32x32x16_f16(A[2], B[1], acc[2][1], 0, 0, 0); \
    acc[3][0] = __builtin_amdgcn_mfma_f32_32x32x16_f16(A[3], B[0], acc[3][0], 0, 0, 0); \
    acc[3][1] = __builtin_amdgcn_mfma_f32_32x32x16_f16(A[3], B[1], acc[3][1], 0, 0, 0); \
  } while (0)

#define LOAD_SET(A, B, sbase)                                                 \
  do {                                                                        \
    const ushort_t* A_ = pa + (sbase);                                        \
    const ushort_t* B_ = pb + (sbase);                                        \
    A[0] = *(const half8*)(A_);                                               \
    A[1] = *(const half8*)(A_ + 512);                                         \
    A[2] = *(const half8*)(A_ + 1024);                                        \
    A[3] = *(const half8*)(A_ + 1536);                                        \
    B[0] = *(const half8*)(B_);                                               \
    B[1] = *(const half8*)(B_ + 512);                                         \
  } while (0)

// VN: 4 => vmcnt(4)+barrier; 0 => vmcnt(0)+barrier; -2 => no end sync.
// LOAD2: second-half prefetch exists (false only for the last phase).
template <bool STG, int VN, bool LOAD2>
__device__ __forceinline__ void gemm_phase(
    int q, const ushort_t* __restrict__ Ag, const ushort_t* __restrict__ Bg,
    int m0, int n0, int tid, ushort_t* lds,
    const ushort_t* pa, const ushort_t* pb,
    half8 (&a0)[4], half8 (&b0)[2], half8 (&a1)[4], half8 (&b1)[2],
    f32x16 (&acc)[4][2]) {
  if constexpr (STG) stage_unit(q + 3, Ag, Bg, m0, n0, tid, lds);
  // ---- first half: prefetch set1 = frags(2q+1) from unit q, slice 1
  {
    const int sb = ((q & 2) << 14) + ((q & 1) << 13) + 4096;
    LOAD_SET(a1, b1, sb);
  }
  SB();
  asm volatile("s_waitcnt lgkmcnt(6)" ::: "memory");  // set0 drained
  SB();
  __builtin_amdgcn_s_setprio(1);
  MFMA8(a0, b0);
  __builtin_amdgcn_s_setprio(0);
  SB();
  // ---- second half: prefetch set0 = frags(2q+2) from unit q+1, slice 0
  if constexpr (LOAD2) {
    const int u = q + 1;
    const int sb = ((u & 2) << 14) + ((u & 1) << 13);
    LOAD_SET(a0, b0, sb);
    SB();
    asm volatile("s_waitcnt lgkmcnt(6)" ::: "memory");  // set1 drained
  } else {
    asm volatile("s_waitcnt lgkmcnt(0)" ::: "memory");  // set1 drained
  }
  SB();
  __builtin_amdgcn_s_setprio(1);
  MFMA8(a1, b1);
  __builtin_amdgcn_s_setprio(0);
  SB();
  if constexpr (VN == 4)      asm volatile("s_waitcnt vmcnt(4)" ::: "memory");
  else if constexpr (VN == 0) asm volatile("s_waitcnt vmcnt(0)" ::: "memory");
  if constexpr (VN >= 0) {
    __builtin_amdgcn_s_barrier();
    asm volatile("" ::: "memory");
  }
}

__global__ __launch_bounds__(512, 2) void gemm256_kernel(
    const ushort_t* __restrict__ Xb, const ushort_t* __restrict__ Wt,
    const float* __restrict__ bias, float* __restrict__ out) {
  __shared__ __align__(16) ushort_t lds[65536];   // 128 KiB, ring of 4 units
  const int tid  = threadIdx.x;
  const int lane = tid & 63;
  const int wid  = tid >> 6;
  const int wm   = wid & 1;        // wave row (m) 0..1
  const int wn   = wid >> 1;       // wave col (n) 0..3
  const int m0   = blockIdx.x * 256;   // m fastest: B panel L3-resident
  const int n0   = blockIdx.y * 256;
  f32x16 acc[4][2] = {};

  // lane-pure part of the frag address (slot swizzle folded in)
  const int loff = (lane & 31) * 16 + (((lane >> 5) ^ ((lane >> 2) & 1)) << 3);
  const ushort_t* pa = lds + loff + wm * 2048;
  const ushort_t* pb = lds + loff + 16384 + wn * 1024;

  half8 a0[4], b0[2], a1[4], b1[2];

  // prologue: units 0,1,2 in flight; vmcnt(4) -> units 0 AND 1 landed
  stage_unit(0, Xb, Wt, m0, n0, tid, lds);
  stage_unit(1, Xb, Wt, m0, n0, tid, lds);
  stage_unit(2, Xb, Wt, m0, n0, tid, lds);
  asm volatile("s_waitcnt vmcnt(4)" ::: "memory");
  __builtin_amdgcn_s_barrier();
  asm volatile("" ::: "memory");
  LOAD_SET(a0, b0, 0);            // set0 = frags(0): unit 0, slice 0
  SB();

  // 128 phases (32-k units); 2 k-steps each. Unroll 4 folds ring indices.
#pragma unroll 4
  for (int q = 0; q < 124; ++q)
    gemm_phase<true, 4, true>(q, Xb, Wt, m0, n0, tid, lds, pa, pb,
                              a0, b0, a1, b1, acc);
  gemm_phase<true,  4, true >(124, Xb, Wt, m0, n0, tid, lds, pa, pb, a0, b0, a1, b1, acc);
  gemm_phase<false, 0, true >(125, Xb, Wt, m0, n0, tid, lds, pa, pb, a0, b0, a1, b1, acc);
  gemm_phase<false, -2, true>(126, Xb, Wt, m0, n0, tid, lds, pa, pb, a0, b0, a1, b1, acc);
  gemm_phase<false, -2, false>(127, Xb, Wt, m0, n0, tid, lds, pa, pb, a0, b0, a1, b1, acc);

  // epilogue: 32x32 C/D layout col=lane&31, row=(reg&3)+8*(reg>>2)+4*(lane>>5)
#pragma unroll
  for (int jj = 0; jj < 2; ++jj) {
    int n = n0 + wn * 64 + jj * 32 + (lane & 31);
    float bv = bias[n];
#pragma unroll
    for (int i = 0; i < 4; ++i) {
      int mbase = m0 + wm * 128 + i * 32 + ((lane >> 5) << 2);
#pragma unroll
      for (int reg = 0; reg < 16; ++reg) {
        int m = mbase + (reg & 3) + ((reg >> 2) << 3);
        __builtin_nontemporal_store(acc[i][jj][reg] + bv,
                                    out + (size_t)m * N_DIM + n);
      }
    }
  }
}

// ---------------------------------------------------------------------------
// Fallback GEMM (R3): 128x128x64 block tile, 32x32x16 MFMA — used only when
// the workspace is too small for the materialized-Wt/Xb fast path.
template <int APRE, int BPRE>
__global__ __launch_bounds__(256) void gemm_kernel(
    const ushort_t* __restrict__ Xb, const float* __restrict__ Xf,
    const ushort_t* __restrict__ Wt,
    const int* __restrict__ qw, const int* __restrict__ qz,
    const float* __restrict__ sc,
    const float* __restrict__ bias, float* __restrict__ out) {
  __shared__ __align__(16) ushort_t lsA[128 * 64];
  __shared__ __align__(16) ushort_t lsB[128 * 64];
  const int tid  = threadIdx.x;
  const int lane = tid & 63;
  const int wid  = tid >> 6;
  const int wm   = wid & 1;
  const int wn   = wid >> 1;
  const int m0   = blockIdx.x * 128;
  const int n0   = blockIdx.y * 128;

  f32x16 acc[2][2] = {};

  for (int kt = 0; kt < K_DIM / 64; ++kt) {
    const int kb = kt * 64;
    if constexpr (APRE) {
#pragma unroll
      for (int i = 0; i < 4; ++i) {
        int cid = i * 256 + tid;
        int r = cid >> 3, scol = cid & 7;
        int c = scol ^ (r & 7);
        GLDS16(Xb + (size_t)(m0 + r) * K_DIM + kb + c * 8, lsA + cid * 8);
      }
    } else {
#pragma unroll
      for (int i = 0; i < 4; ++i) {
        int cid = i * 256 + tid;
        int r = cid >> 3, scol = cid & 7;
        int c = scol ^ (r & 7);
        const float* src = Xf + (size_t)(m0 + r) * K_DIM + kb + c * 8;
        float4 a = *(const float4*)src;
        float4 b = *(const float4*)(src + 4);
        us8 o;
        o[0] = f2h(a.x); o[1] = f2h(a.y); o[2] = f2h(a.z); o[3] = f2h(a.w);
        o[4] = f2h(b.x); o[5] = f2h(b.y); o[6] = f2h(b.z); o[7] = f2h(b.w);
        *(us8*)(lsA + cid * 8) = o;
      }
    }
    if constexpr (BPRE) {
#pragma unroll
      for (int i = 0; i < 4; ++i) {
        int cid = i * 256 + tid;
        int r = cid >> 3, scol = cid & 7;
        int c = scol ^ (r & 7);
        GLDS16(Wt + (size_t)(n0 + r) * K_DIM + kb + c * 8, lsB + cid * 8);
      }
    } else {
#pragma unroll
      for (int i = 0; i < 4; ++i) {
        int wi = i * 256 + tid;
        int kl = wi >> 4, cw = wi & 15;
        int k = kb + kl;
        int g = k >> 7;
        int qword = qw[(size_t)k * NP + (n0 >> 3) + cw];
        int zword = qz[g * NP + (n0 >> 3) + cw];
        float4 s0 = *(const float4*)(sc + (size_t)g * N_DIM + n0 + cw * 8);
        float4 s1 = *(const float4*)(sc + (size_t)g * N_DIM + n0 + cw * 8 + 4);
        float sv[8] = {s0.x, s0.y, s0.z, s0.w, s1.x, s1.y, s1.z, s1.w};
#pragma unroll
        for (int j = 0; j < 8; ++j) {
          int nl = cw * 8 + j;
          int q = (qword >> (4 * j)) & 0xF;
          int z = (zword >> (4 * j)) & 0xF;
          lsB[nl * 64 + (((kl >> 3) ^ (nl & 7)) << 3) + (kl & 7)] =
              f2h((float)(q - z) * sv[j]);
        }
      }
    }
    __syncthreads();
#pragma unroll
    for (int ks = 0; ks < 4; ++ks) {
      half8 af[2], bfr[2];
      const int h = lane >> 5;
      const int c = ks * 2 + h;
#pragma unroll
      for (int i = 0; i < 2; ++i) {
        int row = wm * 64 + i * 32 + (lane & 31);
        af[i] = *(const half8*)(lsA + (row * 8 + (c ^ (row & 7))) * 8);
      }
#pragma unroll
      for (int jj = 0; jj < 2; ++jj) {
        int row = wn * 64 + jj * 32 + (lane & 31);
        bfr[jj] = *(const half8*)(lsB + (row * 8 + (c ^ (row & 7))) * 8);
      }
#pragma unroll
      for (int i = 0; i < 2; ++i)
#pragma unroll
        for (int jj = 0; jj < 2; ++jj)
          acc[i][jj] = __builtin_amdgcn_mfma_f32_32x32x16_f16(
              af[i], bfr[jj], acc[i][jj], 0, 0, 0);
    }
    __syncthreads();
  }

#pragma unroll
  for (int jj = 0; jj < 2; ++jj) {
    int n = n0 + wn * 64 + jj * 32 + (lane & 31);
    float bv = bias[n];
#pragma unroll
    for (int i = 0; i < 2; ++i) {
      int mbase = m0 + wm * 64 + i * 32 + ((lane >> 5) << 2);
#pragma unroll
      for (int reg = 0; reg < 16; ++reg) {
        int m = mbase + (reg & 3) + ((reg >> 2) << 3);
        __builtin_nontemporal_store(acc[i][jj][reg] + bv,
                                    out + (size_t)m * N_DIM + n);
      }
    }
  }
}

// ---------------------------------------------------------------------------
extern "C" void kernel_launch(void* const* d_in, const int* in_sizes, int n_in,
                              void* d_out, int out_size, void* d_ws, size_t ws_size,
                              hipStream_t stream) {
  const float* x    = (const float*)d_in[0];
  const int*   qw   = (const int*)d_in[1];
  const int*   qz   = (const int*)d_in[2];
  const float* sc   = (const float*)d_in[3];
  const float* bias = (const float*)d_in[4];
  float*       out  = (float*)d_out;
  // d_in[5] = groupsize (=128, hardcoded)

  const size_t WT_BYTES = (size_t)N_DIM * K_DIM * 2;  // 96 MiB
  const size_t XB_BYTES = (size_t)M_DIM * K_DIM * 2;  // 32 MiB
  ushort_t* Wt = (ushort_t*)d_ws;
  ushort_t* Xb = (ushort_t*)((char*)d_ws + WT_BYTES);
  const bool hasWt = ws_size >= WT_BYTES;
  const bool hasXb = ws_size >= WT_BYTES + XB_BYTES;

  if (hasXb) {
    prep_kernel<<<DQ_BLOCKS + CVT_BLOCKS, 256, 0, stream>>>(qw, qz, sc, Wt, x, Xb);
    dim3 grid256(M_DIM / 256, N_DIM / 256);  // (16, 48): m fastest
    gemm256_kernel<<<grid256, 512, 0, stream>>>(Xb, Wt, bias, out);
  } else if (hasWt) {
    dim3 grid(M_DIM / 128, N_DIM / 128);
    prep_kernel<<<DQ_BLOCKS, 256, 0, stream>>>(qw, qz, sc, Wt, x, nullptr);
    gemm_kernel<0, 1><<<grid, 256, 0, stream>>>(nullptr, x, Wt, qw, qz, sc, bias, out);
  } else {
    dim3 grid(M_DIM / 128, N_DIM / 128);
    gemm_kernel<0, 0><<<grid, 256, 0, stream>>>(nullptr, x, nullptr, qw, qz, sc, bias, out);
  }
}

// Round 4
// 591.077 us; speedup vs baseline: 1.1542x; 1.1542x over previous
//
#include <hip/hip_runtime.h>

// Problem constants (QuantLinear: x[M,K] fp32, qweight[K,N/8] i32, qzeros[G,N/8] i32,
// scales[G,N] fp32, bias[N] fp32, groupsize=128) -> out[M,N] fp32
#define M_DIM 4096
#define N_DIM 12288
#define K_DIM 4096
#define NP    1536        // N/8 packed words per row
#define GS    128

typedef unsigned short ushort_t;
typedef _Float16 half8 __attribute__((ext_vector_type(8)));
typedef unsigned short us8 __attribute__((ext_vector_type(8)));
typedef unsigned short us16 __attribute__((ext_vector_type(16)));
typedef float f32x16 __attribute__((ext_vector_type(16)));
typedef float f32x4 __attribute__((ext_vector_type(4)));

__device__ __forceinline__ unsigned short f2h(float f) {
  _Float16 h = (_Float16)f;
  return __builtin_bit_cast(unsigned short, h);
}

// async global->LDS, 16B per lane; LDS dst is wave-uniform base + lane*16
#define GLDS16(G, L) __builtin_amdgcn_global_load_lds(                      \
    (const __attribute__((address_space(1))) void*)(G),                     \
    (__attribute__((address_space(3))) void*)(L), 16, 0, 0)

// R7 tiled workspace layout ("unit" = 32-k step of one 256-row panel):
//   unit image = 16KB = [slice s:2][row r:256][slot t0:2][8 f16]
//   halfword offset  = s*4096 + r*16 + t0*8
//   content          = operand[panel*256 + r][u*32 + s*16 + (t0^((r>>2)&1))*8 + j]
// This is byte-identical to what the R5 GEMM's stage placed in LDS, so the
// GEMM's glds source is simply unit_base + tid*16B (linear), and all
// read-side code keeps the R5 (measured conflict-free) addressing.
// WtT: 48 n-panels x 128 units; XbT: 16 m-panels x 128 units.

#define DQ_BLOCKS (48 * 128)     // 6144: one B-unit each
#define CVT_BLOCKS (16 * 128)    // 2048: one A-unit each

// ---------------------------------------------------------------------------
// Fused prep. DQ blocks: dequant qweight -> WtT tiled units (streaming 32B/th
// writes). CVT blocks: x fp32 -> f16 XbT tiled units (128B/thread reads,
// 32B/thread writes, both contiguous per wave).
__global__ __launch_bounds__(256) void prep_kernel(
    const int* __restrict__ qw, const int* __restrict__ qz,
    const float* __restrict__ sc, ushort_t* __restrict__ wtT,
    const float* __restrict__ x, ushort_t* __restrict__ xbT) {
  __shared__ int ldsQ[32 * 32];
  __shared__ int ldsZ[32];
  const int tid = threadIdx.x;
  const int bx  = blockIdx.x;
  if (bx >= DQ_BLOCKS) {
    // ---- x fp32 -> f16 into tiled A-unit (pm, u)
    const int idx = bx - DQ_BLOCKS;
    const int pm = idx >> 7, u = idx & 127;
    const int r  = tid;                  // m-local 0..255
    const int rb = (r >> 2) & 1;
    const float* src = x + (size_t)(pm * 256 + r) * K_DIM + u * 32;
    ushort_t* dst = xbT + (size_t)(pm * 128 + u) * 8192 + r * 16;
#pragma unroll
    for (int sl = 0; sl < 2; ++sl) {
      float4 f0 = *(const float4*)(src + sl * 16);
      float4 f1 = *(const float4*)(src + sl * 16 + 4);
      float4 f2 = *(const float4*)(src + sl * 16 + 8);
      float4 f3 = *(const float4*)(src + sl * 16 + 12);
      us8 lo, hi;
      lo[0] = f2h(f0.x); lo[1] = f2h(f0.y); lo[2] = f2h(f0.z); lo[3] = f2h(f0.w);
      lo[4] = f2h(f1.x); lo[5] = f2h(f1.y); lo[6] = f2h(f1.z); lo[7] = f2h(f1.w);
      hi[0] = f2h(f2.x); hi[1] = f2h(f2.y); hi[2] = f2h(f2.z); hi[3] = f2h(f2.w);
      hi[4] = f2h(f3.x); hi[5] = f2h(f3.y); hi[6] = f2h(f3.z); hi[7] = f2h(f3.w);
      us8 s0 = rb ? hi : lo;             // slot t0 holds k-half t0^rb
      us8 s1 = rb ? lo : hi;
      us16 o = __builtin_shufflevector(s0, s1, 0, 1, 2, 3, 4, 5, 6, 7,
                                       8, 9, 10, 11, 12, 13, 14, 15);
      *(us16*)(dst + sl * 4096) = o;     // 32B store, wave-contiguous
    }
    return;
  }
  // ---- dequant B-unit (p, u): 256 n x 32 k
  const int p  = bx >> 7;          // n-panel 0..47
  const int u  = bx & 127;         // k-unit 0..127
  const int w0 = p << 5;           // first packed word col (32 words = 256 n)
  const int g  = u >> 2;           // 32-k unit inside one 128-group
  const int kb = u << 5;
  {
    // stage qw [32 rows][32 words], XOR'd for conflict-free transposed read
    int row = tid >> 3, wq = tid & 7;
    int4 v = *(const int4*)(qw + (size_t)(kb + row) * NP + w0 + wq * 4);
    ldsQ[row * 32 + ((wq * 4 + 0) ^ row)] = v.x;
    ldsQ[row * 32 + ((wq * 4 + 1) ^ row)] = v.y;
    ldsQ[row * 32 + ((wq * 4 + 2) ^ row)] = v.z;
    ldsQ[row * 32 + ((wq * 4 + 3) ^ row)] = v.w;
  }
  if (tid < 32) ldsZ[tid] = qz[(size_t)g * NP + w0 + tid];
  __syncthreads();
  const int r   = tid;             // n-local 0..255
  const int col = r >> 3;
  const int j4  = (r & 7) * 4;
  const int rb  = (r >> 2) & 1;
  const int z   = (ldsZ[col] >> j4) & 0xF;
  const float s = sc[(size_t)g * N_DIM + p * 256 + r];
  ushort_t* dst = wtT + (size_t)(p * 128 + u) * 8192 + r * 16;
#pragma unroll
  for (int sl = 0; sl < 2; ++sl) {
    us8 e0, e1;                    // k-halves 0 (sl*16+0..7) and 1 (sl*16+8..15)
#pragma unroll
    for (int j = 0; j < 8; ++j) {
      int k0 = sl * 16 + j;
      int k1 = k0 + 8;
      int q0 = (ldsQ[k0 * 32 + (col ^ k0)] >> j4) & 0xF;
      int q1 = (ldsQ[k1 * 32 + (col ^ k1)] >> j4) & 0xF;
      e0[j] = f2h((float)(q0 - z) * s);
      e1[j] = f2h((float)(q1 - z) * s);
    }
    us8 s0 = rb ? e1 : e0;         // slot t0 holds k-half t0^rb
    us8 s1 = rb ? e0 : e1;
    us16 o = __builtin_shufflevector(s0, s1, 0, 1, 2, 3, 4, 5, 6, 7,
                                     8, 9, 10, 11, 12, 13, 14, 15);
    *(us16*)(dst + sl * 4096) = o;   // 32B store, wave-contiguous
  }
}

// ---------------------------------------------------------------------------
// R7 GEMM = R5 GEMM verbatim (370us, MfmaUtil 53%, bank-conflicts 0) except
// stage_unit: sources are now the pre-tiled/pre-swizzled WtT/XbT units, so
// each glds reads linearly (unit_base + tid*16B). LDS image unchanged.
//
// 256x256 tile, BK=64 (2 units of 32k), 512 threads = 8 waves (2m x 4n),
// wave tile 128x64 of mfma_f32_16x16x32_f16. Split-wait interleave:
// reads in consumption order, counted lgkmcnt(7-i) before MFMA row i,
// ONE barrier per phase, end-of-phase vmcnt(8) (units p+2,p+3 in flight).

__device__ __forceinline__ void stage_unit(
    int u, const ushort_t* __restrict__ AT, const ushort_t* __restrict__ BT,
    int pm, int pn, int tid, ushort_t* lds) {
  const int b  = (u >> 1) & 1;
  const int ks = u & 1;
  ushort_t* dA = lds + b * 32768 + ks * 8192 + tid * 8;
  ushort_t* dB = dA + 16384;
  const ushort_t* sA = AT + (size_t)(pm * 128 + u) * 8192 + tid * 8;
  const ushort_t* sB = BT + (size_t)(pn * 128 + u) * 8192 + tid * 8;
  GLDS16(sA,        dA);          // A slice 0
  GLDS16(sA + 4096, dA + 4096);   // A slice 1
  GLDS16(sB,        dB);          // B slice 0
  GLDS16(sB + 4096, dB + 4096);   // B slice 1
}

template <int N>
__device__ __forceinline__ void wait_lgkm() {
  if constexpr (N == 0)      asm volatile("s_waitcnt lgkmcnt(0)" ::: "memory");
  else if constexpr (N == 1) asm volatile("s_waitcnt lgkmcnt(1)" ::: "memory");
  else if constexpr (N == 2) asm volatile("s_waitcnt lgkmcnt(2)" ::: "memory");
  else if constexpr (N == 3) asm volatile("s_waitcnt lgkmcnt(3)" ::: "memory");
  else if constexpr (N == 4) asm volatile("s_waitcnt lgkmcnt(4)" ::: "memory");
  else if constexpr (N == 5) asm volatile("s_waitcnt lgkmcnt(5)" ::: "memory");
  else if constexpr (N == 6) asm volatile("s_waitcnt lgkmcnt(6)" ::: "memory");
  else if constexpr (N == 7) asm volatile("s_waitcnt lgkmcnt(7)" ::: "memory");
  __builtin_amdgcn_sched_barrier(0);   // rule 18: keep MFMAs below the wait
}

#define SB() __builtin_amdgcn_sched_barrier(0)

template <int VN, bool STG>
__device__ __forceinline__ void gemm_phase(
    int p, const ushort_t* __restrict__ AT, const ushort_t* __restrict__ BT,
    int pm, int pn, int tid, ushort_t* lds, f32x4 (&acc)[8][4]) {
  const int lane = tid & 63;
  const int wid  = tid >> 6;
  const int wm   = wid & 1;        // wave row (m) 0..1
  const int wn   = wid >> 1;       // wave col (n) 0..3
  const int ks   = p & 1;
  const int b    = (p >> 1) & 1;
  // A frag: row = lane&15, k = (lane>>4)*8 + j  (16x16x32 f16 layout).
  // chunk c = lane>>4 -> slice 2ks+(c>>1), k-half h=c&1, slot = h^((row>>2)&1).
  const int c  = lane >> 4;
  const int rl = lane & 15;
  const int sg = (c & 1) ^ ((rl >> 2) & 1);
  const ushort_t* base = lds + b * 32768 + (2 * ks + (c >> 1)) * 4096 + sg * 8;
  const ushort_t* pa = base + (wm * 128 + rl) * 16;
  const ushort_t* pb = base + 16384 + (wn * 64 + rl) * 16;
  half8 af[8], bf[4];
  // ---- issue reads in consumption order; SB pins issue order so counted
  //      lgkm waits map to the right registers.
  af[0] = *(const half8*)(pa);
  bf[0] = *(const half8*)(pb);
  bf[1] = *(const half8*)(pb + 256);
  bf[2] = *(const half8*)(pb + 512);
  bf[3] = *(const half8*)(pb + 768);
  SB();
  af[1] = *(const half8*)(pa + 256);  SB();
  af[2] = *(const half8*)(pa + 512);  SB();
  af[3] = *(const half8*)(pa + 768);  SB();
  af[4] = *(const half8*)(pa + 1024); SB();
  af[5] = *(const half8*)(pa + 1280); SB();
  af[6] = *(const half8*)(pa + 1536); SB();
  af[7] = *(const half8*)(pa + 1792); SB();
  if constexpr (STG) stage_unit(p + 3, AT, BT, pm, pn, tid, lds);
  __builtin_amdgcn_s_setprio(1);
#define MFMA_ROW(i, W)                                                       \
  wait_lgkm<W>();                                                            \
  acc[i][0] = __builtin_amdgcn_mfma_f32_16x16x32_f16(af[i], bf[0], acc[i][0], 0, 0, 0); \
  acc[i][1] = __builtin_amdgcn_mfma_f32_16x16x32_f16(af[i], bf[1], acc[i][1], 0, 0, 0); \
  acc[i][2] = __builtin_amdgcn_mfma_f32_16x16x32_f16(af[i], bf[2], acc[i][2], 0, 0, 0); \
  acc[i][3] = __builtin_amdgcn_mfma_f32_16x16x32_f16(af[i], bf[3], acc[i][3], 0, 0, 0)
  MFMA_ROW(0, 7);
  MFMA_ROW(1, 6);
  MFMA_ROW(2, 5);
  MFMA_ROW(3, 4);
  MFMA_ROW(4, 3);
  MFMA_ROW(5, 2);
  MFMA_ROW(6, 1);
  MFMA_ROW(7, 0);
#undef MFMA_ROW
  __builtin_amdgcn_s_setprio(0);
  if constexpr (VN == 8)      asm volatile("s_waitcnt vmcnt(8)" ::: "memory");
  else if constexpr (VN == 4) asm volatile("s_waitcnt vmcnt(4)" ::: "memory");
  else if constexpr (VN == 0) asm volatile("s_waitcnt vmcnt(0)" ::: "memory");
  if constexpr (VN >= 0) {
    __builtin_amdgcn_s_barrier();
    asm volatile("" ::: "memory");     // fence: next phase's ds_reads stay below
  }
}

__global__ __launch_bounds__(512, 2) void gemm256_kernel(
    const ushort_t* __restrict__ XbT, const ushort_t* __restrict__ WtT,
    const float* __restrict__ bias, float* __restrict__ out) {
  __shared__ __align__(16) ushort_t lds[65536];   // 128 KiB, ring of 4 units
  const int tid = threadIdx.x;
  const int pm  = blockIdx.x;          // m fastest: B panel L3-resident
  const int pn  = blockIdx.y;
  const int m0  = pm * 256;
  const int n0  = pn * 256;
  f32x4 acc[8][4] = {};

  // prologue: units 0,1,2 in flight; vmcnt(8) -> unit 0 landed
  stage_unit(0, XbT, WtT, pm, pn, tid, lds);
  stage_unit(1, XbT, WtT, pm, pn, tid, lds);
  stage_unit(2, XbT, WtT, pm, pn, tid, lds);
  asm volatile("s_waitcnt vmcnt(8)" ::: "memory");
  __builtin_amdgcn_s_barrier();
  asm volatile("" ::: "memory");

  // 128 phases = 64 K-tiles x 2 K-steps. Unroll 4 folds ring indices.
#pragma unroll 4
  for (int p = 0; p < 125; ++p)
    gemm_phase<8, true>(p, XbT, WtT, pm, pn, tid, lds, acc);
  gemm_phase<4,  false>(125, XbT, WtT, pm, pn, tid, lds, acc);
  gemm_phase<0,  false>(126, XbT, WtT, pm, pn, tid, lds, acc);
  gemm_phase<-1, false>(127, XbT, WtT, pm, pn, tid, lds, acc);

  // epilogue: 16x16 C/D layout col=lane&15, row=(lane>>4)*4+reg [m89].
  const int lane = tid & 63;
  const int wm   = (tid >> 6) & 1;
  const int wn   = tid >> 7;
#pragma unroll
  for (int jj = 0; jj < 4; ++jj) {
    int n = n0 + wn * 64 + jj * 16 + (lane & 15);
    float bv = bias[n];
#pragma unroll
    for (int i = 0; i < 8; ++i) {
      int mb = (int)(m0 + wm * 128 + i * 16 + ((lane >> 4) << 2));
#pragma unroll
      for (int r = 0; r < 4; ++r)
        __builtin_nontemporal_store(acc[i][jj][r] + bv,
                                    out + (size_t)(mb + r) * N_DIM + n);
    }
  }
}

// ---------------------------------------------------------------------------
// Fallback GEMM: fully-fused 128x128x64 tile (no workspace) — correctness
// safety net only.
__global__ __launch_bounds__(256) void gemm_fused_kernel(
    const float* __restrict__ Xf,
    const int* __restrict__ qw, const int* __restrict__ qz,
    const float* __restrict__ sc,
    const float* __restrict__ bias, float* __restrict__ out) {
  __shared__ __align__(16) ushort_t lsA[128 * 64];
  __shared__ __align__(16) ushort_t lsB[128 * 64];
  const int tid  = threadIdx.x;
  const int lane = tid & 63;
  const int wid  = tid >> 6;
  const int wm   = wid & 1;
  const int wn   = wid >> 1;
  const int m0   = blockIdx.x * 128;
  const int n0   = blockIdx.y * 128;

  f32x16 acc[2][2] = {};

  for (int kt = 0; kt < K_DIM / 64; ++kt) {
    const int kb = kt * 64;
#pragma unroll
    for (int i = 0; i < 4; ++i) {
      int cid = i * 256 + tid;
      int r = cid >> 3, scol = cid & 7;
      int c = scol ^ (r & 7);
      const float* src = Xf + (size_t)(m0 + r) * K_DIM + kb + c * 8;
      float4 a = *(const float4*)src;
      float4 b = *(const float4*)(src + 4);
      us8 o;
      o[0] = f2h(a.x); o[1] = f2h(a.y); o[2] = f2h(a.z); o[3] = f2h(a.w);
      o[4] = f2h(b.x); o[5] = f2h(b.y); o[6] = f2h(b.z); o[7] = f2h(b.w);
      *(us8*)(lsA + cid * 8) = o;
    }
#pragma unroll
    for (int i = 0; i < 4; ++i) {
      int wi = i * 256 + tid;
      int kl = wi >> 4, cw = wi & 15;
      int k = kb + kl;
      int g = k >> 7;
      int qword = qw[(size_t)k * NP + (n0 >> 3) + cw];
      int zword = qz[g * NP + (n0 >> 3) + cw];
      float4 s0 = *(const float4*)(sc + (size_t)g * N_DIM + n0 + cw * 8);
      float4 s1 = *(const float4*)(sc + (size_t)g * N_DIM + n0 + cw * 8 + 4);
      float sv[8] = {s0.x, s0.y, s0.z, s0.w, s1.x, s1.y, s1.z, s1.w};
#pragma unroll
      for (int j = 0; j < 8; ++j) {
        int nl = cw * 8 + j;
        int q = (qword >> (4 * j)) & 0xF;
        int z = (zword >> (4 * j)) & 0xF;
        lsB[nl * 64 + (((kl >> 3) ^ (nl & 7)) << 3) + (kl & 7)] =
            f2h((float)(q - z) * sv[j]);
      }
    }
    __syncthreads();
#pragma unroll
    for (int ks = 0; ks < 4; ++ks) {
      half8 af[2], bfr[2];
      const int h = lane >> 5;
      const int c = ks * 2 + h;
#pragma unroll
      for (int i = 0; i < 2; ++i) {
        int row = wm * 64 + i * 32 + (lane & 31);
        af[i] = *(const half8*)(lsA + (row * 8 + (c ^ (row & 7))) * 8);
      }
#pragma unroll
      for (int jj = 0; jj < 2; ++jj) {
        int row = wn * 64 + jj * 32 + (lane & 31);
        bfr[jj] = *(const half8*)(lsB + (row * 8 + (c ^ (row & 7))) * 8);
      }
#pragma unroll
      for (int i = 0; i < 2; ++i)
#pragma unroll
        for (int jj = 0; jj < 2; ++jj)
          acc[i][jj] = __builtin_amdgcn_mfma_f32_32x32x16_f16(
              af[i], bfr[jj], acc[i][jj], 0, 0, 0);
    }
    __syncthreads();
  }

#pragma unroll
  for (int jj = 0; jj < 2; ++jj) {
    int n = n0 + wn * 64 + jj * 32 + (lane & 31);
    float bv = bias[n];
#pragma unroll
    for (int i = 0; i < 2; ++i) {
      int mbase = m0 + wm * 64 + i * 32 + ((lane >> 5) << 2);
#pragma unroll
      for (int reg = 0; reg < 16; ++reg) {
        int m = mbase + (reg & 3) + ((reg >> 2) << 3);
        __builtin_nontemporal_store(acc[i][jj][reg] + bv,
                                    out + (size_t)m * N_DIM + n);
      }
    }
  }
}

// ---------------------------------------------------------------------------
extern "C" void kernel_launch(void* const* d_in, const int* in_sizes, int n_in,
                              void* d_out, int out_size, void* d_ws, size_t ws_size,
                              hipStream_t stream) {
  const float* x    = (const float*)d_in[0];
  const int*   qw   = (const int*)d_in[1];
  const int*   qz   = (const int*)d_in[2];
  const float* sc   = (const float*)d_in[3];
  const float* bias = (const float*)d_in[4];
  float*       out  = (float*)d_out;
  // d_in[5] = groupsize (=128, hardcoded)

  const size_t WT_BYTES = (size_t)N_DIM * K_DIM * 2;  // 96 MiB tiled units
  const size_t XB_BYTES = (size_t)M_DIM * K_DIM * 2;  // 32 MiB tiled units
  ushort_t* WtT = (ushort_t*)d_ws;
  ushort_t* XbT = (ushort_t*)((char*)d_ws + WT_BYTES);
  const bool hasWs = ws_size >= WT_BYTES + XB_BYTES;

  if (hasWs) {
    prep_kernel<<<DQ_BLOCKS + CVT_BLOCKS, 256, 0, stream>>>(qw, qz, sc, WtT, x, XbT);
    dim3 grid256(M_DIM / 256, N_DIM / 256);  // (16, 48): m fastest
    gemm256_kernel<<<grid256, 512, 0, stream>>>(XbT, WtT, bias, out);
  } else {
    dim3 grid(M_DIM / 128, N_DIM / 128);
    gemm_fused_kernel<<<grid, 256, 0, stream>>>(x, qw, qz, sc, bias, out);
  }
}